// Round 1
// 11727.524 us; speedup vs baseline: 2.3134x; 2.3134x over previous
//
#include <hip/hip_runtime.h>
#include <math.h>

#define D_MODEL 1024
#define NHEAD 16
#define HEADD 64
#define NLAYER 8
#define BATCH 2
#define SEQ 1024
#define VOCAB 50257
#define ROWS (BATCH*SEQ)   // 2048
#define BKK 16

// ---------------- embedding: x = tok_emb[idx] + pos_emb[t] ----------------
__global__ void embed_kernel(const int* __restrict__ idx, const float* __restrict__ tok,
                             const float* __restrict__ pos, float* __restrict__ x) {
    int row = blockIdx.x;            // 0..ROWS-1,  row = b*SEQ + t
    int t = row % SEQ;
    int v = idx[row];
    const float* tr = tok + (size_t)v * D_MODEL;
    const float* pr = pos + (size_t)t * D_MODEL;
    float* xr = x + (size_t)row * D_MODEL;
    for (int i = threadIdx.x; i < D_MODEL; i += blockDim.x)
        xr[i] = tr[i] + pr[i];
}

// ---------------- layernorm: one block (256 thr) per row ----------------
__global__ void ln_kernel(const float* __restrict__ x, const float* __restrict__ g,
                          const float* __restrict__ b, float* __restrict__ y) {
    __shared__ float sh1[4], sh2[4];
    int row = blockIdx.x;
    const float* xr = x + (size_t)row * D_MODEL;
    float* yr = y + (size_t)row * D_MODEL;
    float s = 0.f, sq = 0.f;
    for (int i = threadIdx.x; i < D_MODEL; i += 256) {
        float v = xr[i]; s += v; sq += v * v;
    }
    #pragma unroll
    for (int off = 32; off; off >>= 1) {
        s  += __shfl_xor(s,  off, 64);
        sq += __shfl_xor(sq, off, 64);
    }
    int w = threadIdx.x >> 6, lane = threadIdx.x & 63;
    if (lane == 0) { sh1[w] = s; sh2[w] = sq; }
    __syncthreads();
    s  = sh1[0] + sh1[1] + sh1[2] + sh1[3];
    sq = sh2[0] + sh2[1] + sh2[2] + sh2[3];
    float mean = s * (1.f / D_MODEL);
    float var  = sq * (1.f / D_MODEL) - mean * mean;
    float inv  = rsqrtf(var + 1e-5f);
    for (int i = threadIdx.x; i < D_MODEL; i += 256)
        yr[i] = (xr[i] - mean) * inv * g[i] + b[i];
}

// ---------------- tiled SGEMM ----------------
// BM = 16*TM rows, BN = 16*TN cols, 256 threads (16x16), TMxTN per thread.
// Split-64 col/row mapping: element (ri*64 + ty*4+i, cj*64 + tx*4+j) keeps every
// LDS read a <=2-way bank conflict (free) instead of 4-way at stride tx*8.
// TRANSB=false: B is [K,N] row-major.  TRANSB=true: B is [N,K] row-major.
template<int TM, int TN, bool TRANSB>
__global__ __launch_bounds__(256)
void gemm_kernel(const float* __restrict__ A, const float* __restrict__ B,
                 const float* __restrict__ bias, const float* __restrict__ res,
                 float* __restrict__ C, int M, int N, int K, int dogelu) {
    constexpr int BM = 16 * TM, BN = 16 * TN;
    static_assert(!TRANSB || BN == 128, "TRANSB loader assumes BN==128");
    __shared__ float As[BKK][BM + 4];
    __shared__ float Bs[BKK][BN + 4];
    int tid = threadIdx.x;              // 0..255
    int tx = tid & 15, ty = tid >> 4;
    int m0 = blockIdx.y * BM;
    int n0 = blockIdx.x * BN;
    float acc[TM][TN] = {};
    for (int k0 = 0; k0 < K; k0 += BKK) {
        // ---- stage A tile (BM x 16), transposed into As[k][m] ----
        #pragma unroll
        for (int iv = 0; iv < BM / 64; iv++) {
            int fid = tid + 256 * iv;           // 0..BM*4-1 float4 id
            int r = fid >> 2, c = (fid & 3) * 4;
            const float4 v = *(const float4*)&A[(size_t)(m0 + r) * K + k0 + c];
            As[c + 0][r] = v.x; As[c + 1][r] = v.y;
            As[c + 2][r] = v.z; As[c + 3][r] = v.w;
        }
        // ---- stage B tile (16 x BN) ----
        if (!TRANSB) {
            #pragma unroll
            for (int iv = 0; iv < BN / 64; iv++) {
                int fid = tid + 256 * iv;       // 0..BN*4-1
                int rr = fid / (BN / 4), cc = (fid % (BN / 4)) * 4;
                int n = n0 + cc;
                float4 v = make_float4(0.f, 0.f, 0.f, 0.f);
                if (n < N) v = *(const float4*)&B[(size_t)(k0 + rr) * N + n];
                *(float4*)&Bs[rr][cc] = v;
            }
        } else {
            int c = tid >> 1;                   // n col within tile, 0..127
            int kk0 = (tid & 1) * 8;
            int n = n0 + c;
            #pragma unroll
            for (int u = 0; u < 2; u++) {
                float4 v = make_float4(0.f, 0.f, 0.f, 0.f);
                if (n < N) v = *(const float4*)&B[(size_t)n * K + k0 + kk0 + u * 4];
                Bs[kk0 + u * 4 + 0][c] = v.x;
                Bs[kk0 + u * 4 + 1][c] = v.y;
                Bs[kk0 + u * 4 + 2][c] = v.z;
                Bs[kk0 + u * 4 + 3][c] = v.w;
            }
        }
        __syncthreads();
        #pragma unroll
        for (int kk = 0; kk < BKK; kk++) {
            float a[TM], bv[TN];
            #pragma unroll
            for (int ri = 0; ri < TM / 4; ri++)
                *(float4*)&a[ri * 4] = *(const float4*)&As[kk][ri * 64 + ty * 4];
            #pragma unroll
            for (int cj = 0; cj < TN / 4; cj++)
                *(float4*)&bv[cj * 4] = *(const float4*)&Bs[kk][cj * 64 + tx * 4];
            #pragma unroll
            for (int i = 0; i < TM; i++)
                #pragma unroll
                for (int j = 0; j < TN; j++)
                    acc[i][j] += a[i] * bv[j];
        }
        __syncthreads();
    }
    // ---- epilogue ----
    bool fast = ((N & 3) == 0) && (n0 + BN <= N);
    #pragma unroll
    for (int ri = 0; ri < TM / 4; ri++) {
        #pragma unroll
        for (int i = 0; i < 4; i++) {
            int m = m0 + ri * 64 + ty * 4 + i;
            #pragma unroll
            for (int cj = 0; cj < TN / 4; cj++) {
                int n = n0 + cj * 64 + tx * 4;
                float v0 = acc[ri * 4 + i][cj * 4 + 0];
                float v1 = acc[ri * 4 + i][cj * 4 + 1];
                float v2 = acc[ri * 4 + i][cj * 4 + 2];
                float v3 = acc[ri * 4 + i][cj * 4 + 3];
                if (bias) {
                    v0 += bias[n + 0]; v1 += bias[n + 1];
                    v2 += bias[n + 2]; v3 += bias[n + 3];
                }
                if (dogelu) {
                    v0 = 0.5f * v0 * (1.f + erff(v0 * 0.70710678118654752f));
                    v1 = 0.5f * v1 * (1.f + erff(v1 * 0.70710678118654752f));
                    v2 = 0.5f * v2 * (1.f + erff(v2 * 0.70710678118654752f));
                    v3 = 0.5f * v3 * (1.f + erff(v3 * 0.70710678118654752f));
                }
                if (fast) {
                    if (res) {
                        const float4 r4 = *(const float4*)&res[(size_t)m * N + n];
                        v0 += r4.x; v1 += r4.y; v2 += r4.z; v3 += r4.w;
                    }
                    float4 o; o.x = v0; o.y = v1; o.z = v2; o.w = v3;
                    *(float4*)&C[(size_t)m * N + n] = o;
                } else {
                    float vv[4] = { v0, v1, v2, v3 };
                    #pragma unroll
                    for (int j = 0; j < 4; j++) {
                        if (n + j < N) {
                            float v = vv[j];
                            if (res) v += res[(size_t)m * N + n + j];
                            C[(size_t)m * N + n + j] = v;
                        }
                    }
                }
            }
        }
    }
}

// ---------------- flash attention: one block per (b, h, 64-query tile) ----------------
// qkv layout: [ROWS, 3*D_MODEL]; q at col h*64, k at D_MODEL + h*64, v at 2*D_MODEL + h*64.
// 256 threads = 16x16; each thread owns 4 q-rows x 4 cols. Online softmax, fp32.
#define QT 64
__global__ __launch_bounds__(256)
void attn_kernel(const float* __restrict__ qkv, float* __restrict__ out) {
    __shared__ float Qs[HEADD][QT + 4];   // [d][q]
    __shared__ float KV[HEADD > QT ? HEADD : QT][QT + 4 > HEADD + 4 ? QT + 4 : HEADD + 4]; // K:[d][k] then V:[k][d]
    __shared__ float Ps[QT][QT + 4];      // [q][k]
    int bx = blockIdx.x;                              // 0..SEQ/QT-1
    // load-balance remap: pair tile m with (NT-1-m) so adjacent blocks sum to equal work
    int qt = (bx & 1) ? (SEQ / QT - 1 - (bx >> 1)) : (bx >> 1);
    int bh = blockIdx.y;
    int b = bh / NHEAD, h = bh % NHEAD;
    int tid = threadIdx.x;
    int tx = tid & 15, ty = tid >> 4;
    const size_t stride = 3 * D_MODEL;
    int q0 = qt * QT;

    // ---- load Q tile transposed: Qs[d][q] ----
    #pragma unroll
    for (int it = 0; it < 4; it++) {
        int fid = tid + 256 * it;
        int r = fid >> 4, c = (fid & 15) * 4;         // r = q row, c = d
        const float4 v = *(const float4*)&qkv[(size_t)(b * SEQ + q0 + r) * stride + h * HEADD + c];
        Qs[c + 0][r] = v.x; Qs[c + 1][r] = v.y;
        Qs[c + 2][r] = v.z; Qs[c + 3][r] = v.w;
    }

    float o[4][4] = {};
    float mprev[4], lsum[4];
    #pragma unroll
    for (int i = 0; i < 4; i++) { mprev[i] = -1e30f; lsum[i] = 0.f; }

    for (int k0 = 0; k0 <= q0; k0 += QT) {
        __syncthreads();   // previous PV (readers of KV-as-V and Ps) done
        // ---- load K tile transposed: KV[d][k] ----
        #pragma unroll
        for (int it = 0; it < 4; it++) {
            int fid = tid + 256 * it;
            int r = fid >> 4, c = (fid & 15) * 4;     // r = k row, c = d
            const float4 v = *(const float4*)&qkv[(size_t)(b * SEQ + k0 + r) * stride + D_MODEL + h * HEADD + c];
            KV[c + 0][r] = v.x; KV[c + 1][r] = v.y;
            KV[c + 2][r] = v.z; KV[c + 3][r] = v.w;
        }
        __syncthreads();
        // ---- S = Q K^T (thread: rows ty*4+i, cols tx*4+j) ----
        float s[4][4] = {};
        #pragma unroll 8
        for (int d = 0; d < HEADD; d++) {
            float a[4], bv[4];
            *(float4*)a  = *(const float4*)&Qs[d][ty * 4];
            *(float4*)bv = *(const float4*)&KV[d][tx * 4];
            #pragma unroll
            for (int i = 0; i < 4; i++)
                #pragma unroll
                for (int j = 0; j < 4; j++)
                    s[i][j] += a[i] * bv[j];
        }
        const bool diag = (k0 == q0);                 // only diagonal tile needs masking
        #pragma unroll
        for (int i = 0; i < 4; i++) {
            #pragma unroll
            for (int j = 0; j < 4; j++) {
                s[i][j] *= 0.125f;                    // 1/sqrt(64)
                if (diag && (k0 + tx * 4 + j > q0 + ty * 4 + i)) s[i][j] = -1e30f;
            }
            float m = fmaxf(fmaxf(s[i][0], s[i][1]), fmaxf(s[i][2], s[i][3]));
            m = fmaxf(m, __shfl_xor(m, 1, 64));
            m = fmaxf(m, __shfl_xor(m, 2, 64));
            m = fmaxf(m, __shfl_xor(m, 4, 64));
            m = fmaxf(m, __shfl_xor(m, 8, 64));       // row max across 16 tx lanes
            float mnew = fmaxf(mprev[i], m);
            float sc = expf(mprev[i] - mnew);
            float rs = 0.f;
            #pragma unroll
            for (int j = 0; j < 4; j++) {
                float p = expf(s[i][j] - mnew);
                s[i][j] = p; rs += p;
            }
            rs += __shfl_xor(rs, 1, 64);
            rs += __shfl_xor(rs, 2, 64);
            rs += __shfl_xor(rs, 4, 64);
            rs += __shfl_xor(rs, 8, 64);
            lsum[i] = lsum[i] * sc + rs;
            mprev[i] = mnew;
            #pragma unroll
            for (int j = 0; j < 4; j++) o[i][j] *= sc;
        }
        // ---- stage P ----
        #pragma unroll
        for (int i = 0; i < 4; i++)
            *(float4*)&Ps[ty * 4 + i][tx * 4] = *(float4*)&s[i][0];
        __syncthreads();   // all S-reads of KV-as-K done; Ps visible
        // ---- load V tile: KV[k][d] ----
        #pragma unroll
        for (int it = 0; it < 4; it++) {
            int fid = tid + 256 * it;
            int r = fid >> 4, c = (fid & 15) * 4;     // r = k row, c = d
            const float4 v = *(const float4*)&qkv[(size_t)(b * SEQ + k0 + r) * stride + 2 * D_MODEL + h * HEADD + c];
            *(float4*)&KV[r][c] = v;
        }
        __syncthreads();
        // ---- O += P V (thread: rows ty*4+i, d-cols tx*4+j) ----
        #pragma unroll 8
        for (int k = 0; k < QT; k++) {
            float a[4], bv[4];
            #pragma unroll
            for (int i = 0; i < 4; i++) a[i] = Ps[ty * 4 + i][k];
            *(float4*)bv = *(const float4*)&KV[k][tx * 4];
            #pragma unroll
            for (int i = 0; i < 4; i++)
                #pragma unroll
                for (int j = 0; j < 4; j++)
                    o[i][j] += a[i] * bv[j];
        }
    }
    // ---- normalize + write ----
    #pragma unroll
    for (int i = 0; i < 4; i++) {
        float inv = 1.f / lsum[i];
        float4 v;
        v.x = o[i][0] * inv; v.y = o[i][1] * inv;
        v.z = o[i][2] * inv; v.w = o[i][3] * inv;
        *(float4*)&out[(size_t)(b * SEQ + q0 + ty * 4 + i) * D_MODEL + h * HEADD + tx * 4] = v;
    }
}

// ---------------- loss: per-row logsumexp, atomicAdd mean into *loss ----------------
__global__ void loss_kernel(const float* __restrict__ logits, const int* __restrict__ tgt,
                            float* __restrict__ loss) {
    __shared__ float sh[4];
    int row = blockIdx.x;
    const float* lr = logits + (size_t)row * VOCAB;
    float m = -1e30f;
    for (int j = threadIdx.x; j < VOCAB; j += 256) m = fmaxf(m, lr[j]);
    #pragma unroll
    for (int off = 32; off; off >>= 1) m = fmaxf(m, __shfl_xor(m, off, 64));
    int w = threadIdx.x >> 6, lane = threadIdx.x & 63;
    if (lane == 0) sh[w] = m;
    __syncthreads();
    m = fmaxf(fmaxf(sh[0], sh[1]), fmaxf(sh[2], sh[3]));
    float s = 0.f;
    for (int j = threadIdx.x; j < VOCAB; j += 256) s += expf(lr[j] - m);
    #pragma unroll
    for (int off = 32; off; off >>= 1) s += __shfl_xor(s, off, 64);
    __syncthreads();            // everyone done reading sh for max
    if (lane == 0) sh[w] = s;
    __syncthreads();
    s = sh[0] + sh[1] + sh[2] + sh[3];
    if (threadIdx.x == 0) {
        float lse = logf(s) + m;
        float li = lr[tgt[row]];
        atomicAdd(loss, (lse - li) * (1.f / ROWS));
    }
}

extern "C" void kernel_launch(void* const* d_in, const int* in_sizes, int n_in,
                              void* d_out, int out_size, void* d_ws, size_t ws_size,
                              hipStream_t stream) {
    const int*   idx     = (const int*)d_in[0];
    const int*   targets = (const int*)d_in[1];
    const float* tok     = (const float*)d_in[2];
    const float* pos     = (const float*)d_in[3];
    const float* ln1_g   = (const float*)d_in[4];
    const float* ln1_b   = (const float*)d_in[5];
    const float* qkv_w   = (const float*)d_in[6];
    const float* proj_w  = (const float*)d_in[7];
    const float* ln2_g   = (const float*)d_in[8];
    const float* ln2_b   = (const float*)d_in[9];
    const float* w1      = (const float*)d_in[10];
    const float* b1      = (const float*)d_in[11];
    const float* w2      = (const float*)d_in[12];
    const float* b2      = (const float*)d_in[13];
    const float* lnf_g   = (const float*)d_in[14];
    const float* lnf_b   = (const float*)d_in[15];
    float* out = (float*)d_out;
    float* ws  = (float*)d_ws;

    // workspace layout (floats)
    float* x    = ws;                                  // 2048*1024
    float* h    = x    + (size_t)ROWS * D_MODEL;       // 2048*1024
    float* qkv  = h    + (size_t)ROWS * D_MODEL;       // 2048*3072
    float* attn = qkv  + (size_t)ROWS * 3 * D_MODEL;   // 2048*1024
    float* mid  = attn + (size_t)ROWS * D_MODEL;       // 2048*4096

    embed_kernel<<<ROWS, 256, 0, stream>>>(idx, tok, pos, x);

    for (int l = 0; l < NLAYER; l++) {
        ln_kernel<<<ROWS, 256, 0, stream>>>(x, ln1_g + l * D_MODEL, ln1_b + l * D_MODEL, h);

        // qkv: 2048 x 3072 x 1024  (64x128 tile -> 24x32 = 768 blocks)
        dim3 gq(3 * D_MODEL / 128, ROWS / 64);
        gemm_kernel<4, 8, false><<<gq, 256, 0, stream>>>(
            h, qkv_w + (size_t)l * D_MODEL * 3 * D_MODEL, nullptr, nullptr,
            qkv, ROWS, 3 * D_MODEL, D_MODEL, 0);

        attn_kernel<<<dim3(SEQ / QT, BATCH * NHEAD), 256, 0, stream>>>(qkv, attn);

        // proj: 2048 x 1024 x 1024  (64x128 -> 8x32 = 256 blocks)
        dim3 gp(D_MODEL / 128, ROWS / 64);
        gemm_kernel<4, 8, false><<<gp, 256, 0, stream>>>(
            attn, proj_w + (size_t)l * D_MODEL * D_MODEL, nullptr, x,
            x, ROWS, D_MODEL, D_MODEL, 0);

        ln_kernel<<<ROWS, 256, 0, stream>>>(x, ln2_g + l * D_MODEL, ln2_b + l * D_MODEL, h);

        // fc1: 2048 x 4096 x 1024  (128x128 -> 32x16 = 512 blocks)
        dim3 gf1(4 * D_MODEL / 128, ROWS / 128);
        gemm_kernel<8, 8, false><<<gf1, 256, 0, stream>>>(
            h, w1 + (size_t)l * D_MODEL * 4 * D_MODEL, b1 + (size_t)l * 4 * D_MODEL, nullptr,
            mid, ROWS, 4 * D_MODEL, D_MODEL, 1);

        // fc2: 2048 x 1024 x 4096  (64x128 -> 8x32 = 256 blocks)
        gemm_kernel<4, 8, false><<<gp, 256, 0, stream>>>(
            mid, w2 + (size_t)l * 4 * D_MODEL * D_MODEL, b2 + (size_t)l * D_MODEL, x,
            x, ROWS, D_MODEL, 4 * D_MODEL, 0);
    }

    ln_kernel<<<ROWS, 256, 0, stream>>>(x, lnf_g, lnf_b, h);

    // logits: 2048 x 50257 x 1024, B = tok_emb [V,K] used transposed (128x128 tile)
    dim3 gl((VOCAB + 127) / 128, ROWS / 128);
    gemm_kernel<8, 8, true><<<gl, 256, 0, stream>>>(
        h, tok, nullptr, nullptr, out, ROWS, VOCAB, D_MODEL, 0);

    hipMemsetAsync(out + (size_t)ROWS * VOCAB, 0, sizeof(float), stream);
    loss_kernel<<<ROWS, 256, 0, stream>>>(out, targets, out + (size_t)ROWS * VOCAB);
}

// Round 2
// 6250.686 us; speedup vs baseline: 4.3403x; 1.8762x over previous
//
#include <hip/hip_runtime.h>
#include <math.h>

#define D_MODEL 1024
#define NHEAD 16
#define HEADD 64
#define NLAYER 8
#define BATCH 2
#define SEQ 1024
#define VOCAB 50257
#define VPAD 50304
#define ROWS (BATCH*SEQ)   // 2048
#define BKK 16

typedef __attribute__((ext_vector_type(8))) short short8v;   // 8 bf16 = 4 VGPR
typedef __attribute__((ext_vector_type(4))) float f32x4;

// split fp32 -> hi/lo bf16 (RTN-even both). x ~= hi + lo with rel err ~2^-17.
__device__ __forceinline__ void split_bf16(float x, unsigned short &h, unsigned short &l) {
    unsigned int u = __float_as_uint(x);
    unsigned int rh = (u + 0x7FFFu + ((u >> 16) & 1u)) & 0xFFFF0000u;
    h = (unsigned short)(rh >> 16);
    float r = x - __uint_as_float(rh);      // exact (Dekker residual)
    unsigned int v = __float_as_uint(r);
    l = (unsigned short)((v + 0x7FFFu + ((v >> 16) & 1u)) >> 16);
}

// ---------------- embedding ----------------
__global__ void embed_kernel(const int* __restrict__ idx, const float* __restrict__ tok,
                             const float* __restrict__ pos, float* __restrict__ x) {
    int row = blockIdx.x;
    int t = row % SEQ;
    int v = idx[row];
    const float* tr = tok + (size_t)v * D_MODEL;
    const float* pr = pos + (size_t)t * D_MODEL;
    float* xr = x + (size_t)row * D_MODEL;
    for (int i = threadIdx.x; i < D_MODEL; i += blockDim.x)
        xr[i] = tr[i] + pr[i];
}

// ---------------- layernorm: fp32 out (y) and/or bf16 hi/lo planes ----------------
__global__ void ln_kernel(const float* __restrict__ x, const float* __restrict__ g,
                          const float* __restrict__ b, float* __restrict__ y,
                          unsigned short* __restrict__ yh, unsigned short* __restrict__ yl) {
    __shared__ float sh1[4], sh2[4];
    int row = blockIdx.x;
    const float* xr = x + (size_t)row * D_MODEL;
    float s = 0.f, sq = 0.f;
    for (int i = threadIdx.x; i < D_MODEL; i += 256) {
        float v = xr[i]; s += v; sq += v * v;
    }
    #pragma unroll
    for (int off = 32; off; off >>= 1) {
        s  += __shfl_xor(s,  off, 64);
        sq += __shfl_xor(sq, off, 64);
    }
    int w = threadIdx.x >> 6, lane = threadIdx.x & 63;
    if (lane == 0) { sh1[w] = s; sh2[w] = sq; }
    __syncthreads();
    s  = sh1[0] + sh1[1] + sh1[2] + sh1[3];
    sq = sh2[0] + sh2[1] + sh2[2] + sh2[3];
    float mean = s * (1.f / D_MODEL);
    float var  = sq * (1.f / D_MODEL) - mean * mean;
    float inv  = rsqrtf(var + 1e-5f);
    for (int i = threadIdx.x; i < D_MODEL; i += 256) {
        float v = (xr[i] - mean) * inv * g[i] + b[i];
        if (y) y[(size_t)row * D_MODEL + i] = v;
        if (yh) {
            unsigned short hs, ls; split_bf16(v, hs, ls);
            yh[(size_t)row * D_MODEL + i] = hs;
            yl[(size_t)row * D_MODEL + i] = ls;
        }
    }
}

// ---------------- weight convert+transpose: W[K][N] fp32 -> Th/Tl [N][K] bf16 ----------------
// grid (N/256, K/8), block 256. Reads coalesced across lanes; 16B writes per lane.
__global__ void convtrans_kernel(const float* __restrict__ W, unsigned short* __restrict__ Th,
                                 unsigned short* __restrict__ Tl, int K, int N) {
    int n  = blockIdx.x * 256 + threadIdx.x;
    int k0 = blockIdx.y * 8;
    short8v hv, lv;
    #pragma unroll
    for (int j = 0; j < 8; j++) {
        float x = W[(size_t)(k0 + j) * N + n];
        unsigned short hs, ls; split_bf16(x, hs, ls);
        hv[j] = (short)hs; lv[j] = (short)ls;
    }
    *(short8v*)(Th + (size_t)n * K + k0) = hv;
    *(short8v*)(Tl + (size_t)n * K + k0) = lv;
}

// ---------------- row convert (no transpose): W[R][D] fp32 -> hi/lo planes ----------------
__global__ void convrow_kernel(const float* __restrict__ W, unsigned short* __restrict__ Th,
                               unsigned short* __restrict__ Tl) {
    size_t base = (size_t)blockIdx.x * D_MODEL;
    int i = threadIdx.x * 4;
    const float4 v = *(const float4*)&W[base + i];
    unsigned short h0,l0,h1,l1,h2,l2,h3,l3;
    split_bf16(v.x,h0,l0); split_bf16(v.y,h1,l1);
    split_bf16(v.z,h2,l2); split_bf16(v.w,h3,l3);
    *(ushort4*)&Th[base + i] = make_ushort4(h0,h1,h2,h3);
    *(ushort4*)&Tl[base + i] = make_ushort4(l0,l1,l2,l3);
}

// ---------------- split-bf16 MFMA GEMM ----------------
// C[M,N] = A[M,K] @ B[K,N] via A~=Ah+Al, B~=Bh+Bl (3 MFMAs: hh + hl + lh).
// A planes: [M][K] bf16. B planes: [N][K] bf16 (pre-transposed). Tile 128x128, BK=32.
// 256 thr = 4 waves in 2x2; each wave 64x64 = 4x4 frags of mfma_f32_16x16x32_bf16.
__global__ __launch_bounds__(256)
void gemm_mfma(const unsigned short* __restrict__ Ah, const unsigned short* __restrict__ Al,
               const unsigned short* __restrict__ Bh, const unsigned short* __restrict__ Bl,
               const float* __restrict__ bias, const float* __restrict__ res,
               float* __restrict__ C, unsigned short* __restrict__ Chi,
               unsigned short* __restrict__ Clo, int M, int N, int K, int dogelu) {
    // pad rows to 40 shorts (80B): rows 0..7 start at banks 0,20,8,28,16,4,24,12
    // -> 16B reads cover all 32 banks over 8 rows, 2-way max (free).
    __shared__ __align__(16) short AhS[128][40];
    __shared__ __align__(16) short AlS[128][40];
    __shared__ __align__(16) short BhS[128][40];
    __shared__ __align__(16) short BlS[128][40];
    int tid = threadIdx.x;
    int lane = tid & 63, wid = tid >> 6;
    int wr = wid >> 1, wc = wid & 1;        // wave 2x2 over (M,N)
    int fr = lane & 15, fq = lane >> 4;     // fragment row / quad
    int m0 = blockIdx.y * 128, n0 = blockIdx.x * 128;

    int r0 = tid >> 2, c0 = (tid & 3) * 8;  // chunk: rows r0, r0+64; 8 bf16 at col c0
    const size_t aoff0 = (size_t)(m0 + r0) * K + c0;
    const size_t aoff1 = (size_t)(m0 + r0 + 64) * K + c0;
    const size_t boff0 = (size_t)(n0 + r0) * K + c0;
    const size_t boff1 = (size_t)(n0 + r0 + 64) * K + c0;

    f32x4 acc[4][4];
    #pragma unroll
    for (int i = 0; i < 4; i++)
        #pragma unroll
        for (int j = 0; j < 4; j++)
            acc[i][j] = (f32x4){0.f, 0.f, 0.f, 0.f};

    for (int k0 = 0; k0 < K; k0 += 32) {
        short8v va0 = *(const short8v*)(Ah + aoff0 + k0);
        short8v va1 = *(const short8v*)(Ah + aoff1 + k0);
        short8v wa0 = *(const short8v*)(Al + aoff0 + k0);
        short8v wa1 = *(const short8v*)(Al + aoff1 + k0);
        short8v vb0 = *(const short8v*)(Bh + boff0 + k0);
        short8v vb1 = *(const short8v*)(Bh + boff1 + k0);
        short8v wb0 = *(const short8v*)(Bl + boff0 + k0);
        short8v wb1 = *(const short8v*)(Bl + boff1 + k0);
        __syncthreads();                    // prev iter's LDS readers done
        *(short8v*)&AhS[r0     ][c0] = va0;
        *(short8v*)&AhS[r0 + 64][c0] = va1;
        *(short8v*)&AlS[r0     ][c0] = wa0;
        *(short8v*)&AlS[r0 + 64][c0] = wa1;
        *(short8v*)&BhS[r0     ][c0] = vb0;
        *(short8v*)&BhS[r0 + 64][c0] = vb1;
        *(short8v*)&BlS[r0     ][c0] = wb0;
        *(short8v*)&BlS[r0 + 64][c0] = wb1;
        __syncthreads();
        short8v fah[4], fal[4], fbh[4], fbl[4];
        #pragma unroll
        for (int f = 0; f < 4; f++) {
            fah[f] = *(const short8v*)&AhS[wr * 64 + f * 16 + fr][fq * 8];
            fal[f] = *(const short8v*)&AlS[wr * 64 + f * 16 + fr][fq * 8];
            fbh[f] = *(const short8v*)&BhS[wc * 64 + f * 16 + fr][fq * 8];
            fbl[f] = *(const short8v*)&BlS[wc * 64 + f * 16 + fr][fq * 8];
        }
        #pragma unroll
        for (int i = 0; i < 4; i++)
            #pragma unroll
            for (int j = 0; j < 4; j++) {
                acc[i][j] = __builtin_amdgcn_mfma_f32_16x16x32_bf16(fah[i], fbh[j], acc[i][j], 0, 0, 0);
                acc[i][j] = __builtin_amdgcn_mfma_f32_16x16x32_bf16(fah[i], fbl[j], acc[i][j], 0, 0, 0);
                acc[i][j] = __builtin_amdgcn_mfma_f32_16x16x32_bf16(fal[i], fbh[j], acc[i][j], 0, 0, 0);
            }
    }
    // epilogue: C/D mapping col=lane&15, row=(lane>>4)*4+v  [m89]
    #pragma unroll
    for (int i = 0; i < 4; i++) {
        int row = m0 + wr * 64 + i * 16 + fq * 4;
        #pragma unroll
        for (int j = 0; j < 4; j++) {
            int col = n0 + wc * 64 + j * 16 + fr;
            if (col < N) {
                float bv = bias ? bias[col] : 0.f;
                #pragma unroll
                for (int v = 0; v < 4; v++) {
                    float xv = acc[i][j][v] + bv;
                    if (dogelu) xv = 0.5f * xv * (1.f + erff(xv * 0.70710678118654752f));
                    size_t off = (size_t)(row + v) * N + col;
                    if (res) xv += res[off];
                    if (C) C[off] = xv;
                    if (Chi) {
                        unsigned short hs, ls; split_bf16(xv, hs, ls);
                        Chi[off] = hs; Clo[off] = ls;
                    }
                }
            }
        }
    }
}

// ---------------- fp32 VALU SGEMM (fallback path, R1-proven) ----------------
template<int TM, int TN, bool TRANSB>
__global__ __launch_bounds__(256)
void gemm_kernel(const float* __restrict__ A, const float* __restrict__ B,
                 const float* __restrict__ bias, const float* __restrict__ res,
                 float* __restrict__ C, int M, int N, int K, int dogelu) {
    constexpr int BM = 16 * TM, BN = 16 * TN;
    static_assert(!TRANSB || BN == 128, "TRANSB loader assumes BN==128");
    __shared__ float As[BKK][BM + 4];
    __shared__ float Bs[BKK][BN + 4];
    int tid = threadIdx.x;
    int tx = tid & 15, ty = tid >> 4;
    int m0 = blockIdx.y * BM;
    int n0 = blockIdx.x * BN;
    float acc[TM][TN] = {};
    for (int k0 = 0; k0 < K; k0 += BKK) {
        #pragma unroll
        for (int iv = 0; iv < BM / 64; iv++) {
            int fid = tid + 256 * iv;
            int r = fid >> 2, c = (fid & 3) * 4;
            const float4 v = *(const float4*)&A[(size_t)(m0 + r) * K + k0 + c];
            As[c + 0][r] = v.x; As[c + 1][r] = v.y;
            As[c + 2][r] = v.z; As[c + 3][r] = v.w;
        }
        if (!TRANSB) {
            #pragma unroll
            for (int iv = 0; iv < BN / 64; iv++) {
                int fid = tid + 256 * iv;
                int rr = fid / (BN / 4), cc = (fid % (BN / 4)) * 4;
                int n = n0 + cc;
                float4 v = make_float4(0.f, 0.f, 0.f, 0.f);
                if (n < N) v = *(const float4*)&B[(size_t)(k0 + rr) * N + n];
                *(float4*)&Bs[rr][cc] = v;
            }
        } else {
            int c = tid >> 1;
            int kk0 = (tid & 1) * 8;
            int n = n0 + c;
            #pragma unroll
            for (int u = 0; u < 2; u++) {
                float4 v = make_float4(0.f, 0.f, 0.f, 0.f);
                if (n < N) v = *(const float4*)&B[(size_t)n * K + k0 + kk0 + u * 4];
                Bs[kk0 + u * 4 + 0][c] = v.x;
                Bs[kk0 + u * 4 + 1][c] = v.y;
                Bs[kk0 + u * 4 + 2][c] = v.z;
                Bs[kk0 + u * 4 + 3][c] = v.w;
            }
        }
        __syncthreads();
        #pragma unroll
        for (int kk = 0; kk < BKK; kk++) {
            float a[TM], bv[TN];
            #pragma unroll
            for (int ri = 0; ri < TM / 4; ri++)
                *(float4*)&a[ri * 4] = *(const float4*)&As[kk][ri * 64 + ty * 4];
            #pragma unroll
            for (int cj = 0; cj < TN / 4; cj++)
                *(float4*)&bv[cj * 4] = *(const float4*)&Bs[kk][cj * 64 + tx * 4];
            #pragma unroll
            for (int i = 0; i < TM; i++)
                #pragma unroll
                for (int j = 0; j < TN; j++)
                    acc[i][j] += a[i] * bv[j];
        }
        __syncthreads();
    }
    bool fast = ((N & 3) == 0) && (n0 + BN <= N);
    #pragma unroll
    for (int ri = 0; ri < TM / 4; ri++) {
        #pragma unroll
        for (int i = 0; i < 4; i++) {
            int m = m0 + ri * 64 + ty * 4 + i;
            #pragma unroll
            for (int cj = 0; cj < TN / 4; cj++) {
                int n = n0 + cj * 64 + tx * 4;
                float v0 = acc[ri * 4 + i][cj * 4 + 0];
                float v1 = acc[ri * 4 + i][cj * 4 + 1];
                float v2 = acc[ri * 4 + i][cj * 4 + 2];
                float v3 = acc[ri * 4 + i][cj * 4 + 3];
                if (bias) {
                    v0 += bias[n + 0]; v1 += bias[n + 1];
                    v2 += bias[n + 2]; v3 += bias[n + 3];
                }
                if (dogelu) {
                    v0 = 0.5f * v0 * (1.f + erff(v0 * 0.70710678118654752f));
                    v1 = 0.5f * v1 * (1.f + erff(v1 * 0.70710678118654752f));
                    v2 = 0.5f * v2 * (1.f + erff(v2 * 0.70710678118654752f));
                    v3 = 0.5f * v3 * (1.f + erff(v3 * 0.70710678118654752f));
                }
                if (fast) {
                    if (res) {
                        const float4 r4 = *(const float4*)&res[(size_t)m * N + n];
                        v0 += r4.x; v1 += r4.y; v2 += r4.z; v3 += r4.w;
                    }
                    float4 o; o.x = v0; o.y = v1; o.z = v2; o.w = v3;
                    *(float4*)&C[(size_t)m * N + n] = o;
                } else {
                    float vv[4] = { v0, v1, v2, v3 };
                    #pragma unroll
                    for (int j = 0; j < 4; j++) {
                        if (n + j < N) {
                            float v = vv[j];
                            if (res) v += res[(size_t)m * N + n + j];
                            C[(size_t)m * N + n + j] = v;
                        }
                    }
                }
            }
        }
    }
}

// ---------------- flash attention (fp32 out and/or bf16 planes) ----------------
#define QT 64
__global__ __launch_bounds__(256)
void attn_kernel(const float* __restrict__ qkv, float* __restrict__ out,
                 unsigned short* __restrict__ outh, unsigned short* __restrict__ outl) {
    __shared__ float Qs[HEADD][QT + 4];
    __shared__ float KV[HEADD > QT ? HEADD : QT][QT + 4 > HEADD + 4 ? QT + 4 : HEADD + 4];
    __shared__ float Ps[QT][QT + 4];
    int bx = blockIdx.x;
    int qt = (bx & 1) ? (SEQ / QT - 1 - (bx >> 1)) : (bx >> 1);
    int bh = blockIdx.y;
    int b = bh / NHEAD, h = bh % NHEAD;
    int tid = threadIdx.x;
    int tx = tid & 15, ty = tid >> 4;
    const size_t stride = 3 * D_MODEL;
    int q0 = qt * QT;

    #pragma unroll
    for (int it = 0; it < 4; it++) {
        int fid = tid + 256 * it;
        int r = fid >> 4, c = (fid & 15) * 4;
        const float4 v = *(const float4*)&qkv[(size_t)(b * SEQ + q0 + r) * stride + h * HEADD + c];
        Qs[c + 0][r] = v.x; Qs[c + 1][r] = v.y;
        Qs[c + 2][r] = v.z; Qs[c + 3][r] = v.w;
    }

    float o[4][4] = {};
    float mprev[4], lsum[4];
    #pragma unroll
    for (int i = 0; i < 4; i++) { mprev[i] = -1e30f; lsum[i] = 0.f; }

    for (int k0 = 0; k0 <= q0; k0 += QT) {
        __syncthreads();
        #pragma unroll
        for (int it = 0; it < 4; it++) {
            int fid = tid + 256 * it;
            int r = fid >> 4, c = (fid & 15) * 4;
            const float4 v = *(const float4*)&qkv[(size_t)(b * SEQ + k0 + r) * stride + D_MODEL + h * HEADD + c];
            KV[c + 0][r] = v.x; KV[c + 1][r] = v.y;
            KV[c + 2][r] = v.z; KV[c + 3][r] = v.w;
        }
        __syncthreads();
        float s[4][4] = {};
        #pragma unroll 8
        for (int d = 0; d < HEADD; d++) {
            float a[4], bv[4];
            *(float4*)a  = *(const float4*)&Qs[d][ty * 4];
            *(float4*)bv = *(const float4*)&KV[d][tx * 4];
            #pragma unroll
            for (int i = 0; i < 4; i++)
                #pragma unroll
                for (int j = 0; j < 4; j++)
                    s[i][j] += a[i] * bv[j];
        }
        const bool diag = (k0 == q0);
        #pragma unroll
        for (int i = 0; i < 4; i++) {
            #pragma unroll
            for (int j = 0; j < 4; j++) {
                s[i][j] *= 0.125f;
                if (diag && (k0 + tx * 4 + j > q0 + ty * 4 + i)) s[i][j] = -1e30f;
            }
            float m = fmaxf(fmaxf(s[i][0], s[i][1]), fmaxf(s[i][2], s[i][3]));
            m = fmaxf(m, __shfl_xor(m, 1, 64));
            m = fmaxf(m, __shfl_xor(m, 2, 64));
            m = fmaxf(m, __shfl_xor(m, 4, 64));
            m = fmaxf(m, __shfl_xor(m, 8, 64));
            float mnew = fmaxf(mprev[i], m);
            float sc = expf(mprev[i] - mnew);
            float rs = 0.f;
            #pragma unroll
            for (int j = 0; j < 4; j++) {
                float p = expf(s[i][j] - mnew);
                s[i][j] = p; rs += p;
            }
            rs += __shfl_xor(rs, 1, 64);
            rs += __shfl_xor(rs, 2, 64);
            rs += __shfl_xor(rs, 4, 64);
            rs += __shfl_xor(rs, 8, 64);
            lsum[i] = lsum[i] * sc + rs;
            mprev[i] = mnew;
            #pragma unroll
            for (int j = 0; j < 4; j++) o[i][j] *= sc;
        }
        #pragma unroll
        for (int i = 0; i < 4; i++)
            *(float4*)&Ps[ty * 4 + i][tx * 4] = *(float4*)&s[i][0];
        __syncthreads();
        #pragma unroll
        for (int it = 0; it < 4; it++) {
            int fid = tid + 256 * it;
            int r = fid >> 4, c = (fid & 15) * 4;
            const float4 v = *(const float4*)&qkv[(size_t)(b * SEQ + k0 + r) * stride + 2 * D_MODEL + h * HEADD + c];
            *(float4*)&KV[r][c] = v;
        }
        __syncthreads();
        #pragma unroll 8
        for (int k = 0; k < QT; k++) {
            float a[4], bv[4];
            #pragma unroll
            for (int i = 0; i < 4; i++) a[i] = Ps[ty * 4 + i][k];
            *(float4*)bv = *(const float4*)&KV[k][tx * 4];
            #pragma unroll
            for (int i = 0; i < 4; i++)
                #pragma unroll
                for (int j = 0; j < 4; j++)
                    o[i][j] += a[i] * bv[j];
        }
    }
    #pragma unroll
    for (int i = 0; i < 4; i++) {
        float inv = 1.f / lsum[i];
        size_t off = (size_t)(b * SEQ + q0 + ty * 4 + i) * D_MODEL + h * HEADD + tx * 4;
        float v0 = o[i][0] * inv, v1 = o[i][1] * inv, v2 = o[i][2] * inv, v3 = o[i][3] * inv;
        if (out) {
            float4 v; v.x = v0; v.y = v1; v.z = v2; v.w = v3;
            *(float4*)&out[off] = v;
        }
        if (outh) {
            unsigned short h0,l0,h1,l1,h2,l2,h3,l3;
            split_bf16(v0,h0,l0); split_bf16(v1,h1,l1);
            split_bf16(v2,h2,l2); split_bf16(v3,h3,l3);
            *(ushort4*)&outh[off] = make_ushort4(h0,h1,h2,h3);
            *(ushort4*)&outl[off] = make_ushort4(l0,l1,l2,l3);
        }
    }
}

// ---------------- loss ----------------
__global__ void loss_kernel(const float* __restrict__ logits, const int* __restrict__ tgt,
                            float* __restrict__ loss) {
    __shared__ float sh[4];
    int row = blockIdx.x;
    const float* lr = logits + (size_t)row * VOCAB;
    float m = -1e30f;
    for (int j = threadIdx.x; j < VOCAB; j += 256) m = fmaxf(m, lr[j]);
    #pragma unroll
    for (int off = 32; off; off >>= 1) m = fmaxf(m, __shfl_xor(m, off, 64));
    int w = threadIdx.x >> 6, lane = threadIdx.x & 63;
    if (lane == 0) sh[w] = m;
    __syncthreads();
    m = fmaxf(fmaxf(sh[0], sh[1]), fmaxf(sh[2], sh[3]));
    float s = 0.f;
    for (int j = threadIdx.x; j < VOCAB; j += 256) s += expf(lr[j] - m);
    #pragma unroll
    for (int off = 32; off; off >>= 1) s += __shfl_xor(s, off, 64);
    __syncthreads();
    if (lane == 0) sh[w] = s;
    __syncthreads();
    s = sh[0] + sh[1] + sh[2] + sh[3];
    if (threadIdx.x == 0) {
        float lse = logf(s) + m;
        float li = lr[tgt[row]];
        atomicAdd(loss, (lse - li) * (1.f / ROWS));
    }
}

extern "C" void kernel_launch(void* const* d_in, const int* in_sizes, int n_in,
                              void* d_out, int out_size, void* d_ws, size_t ws_size,
                              hipStream_t stream) {
    const int*   idx     = (const int*)d_in[0];
    const int*   targets = (const int*)d_in[1];
    const float* tok     = (const float*)d_in[2];
    const float* pos     = (const float*)d_in[3];
    const float* ln1_g   = (const float*)d_in[4];
    const float* ln1_b   = (const float*)d_in[5];
    const float* qkv_w   = (const float*)d_in[6];
    const float* proj_w  = (const float*)d_in[7];
    const float* ln2_g   = (const float*)d_in[8];
    const float* ln2_b   = (const float*)d_in[9];
    const float* w1      = (const float*)d_in[10];
    const float* b1      = (const float*)d_in[11];
    const float* w2      = (const float*)d_in[12];
    const float* b2      = (const float*)d_in[13];
    const float* lnf_g   = (const float*)d_in[14];
    const float* lnf_b   = (const float*)d_in[15];
    float* out = (float*)d_out;

    // ---- MFMA-path workspace layout (bytes) ----
    const size_t o_x    = 0;                       //  8 MB fp32 residual
    const size_t o_qkv  = o_x    + (size_t)ROWS * D_MODEL * 4;        // 24 MB fp32
    const size_t o_hh   = o_qkv  + (size_t)ROWS * 3 * D_MODEL * 4;    //  4 MB
    const size_t o_hl   = o_hh   + (size_t)ROWS * D_MODEL * 2;
    const size_t o_ah   = o_hl   + (size_t)ROWS * D_MODEL * 2;
    const size_t o_al   = o_ah   + (size_t)ROWS * D_MODEL * 2;
    const size_t o_mh   = o_al   + (size_t)ROWS * D_MODEL * 2;        // 8 MB each
    const size_t o_ml   = o_mh   + (size_t)ROWS * 4 * D_MODEL * 2;
    const size_t o_wth  = o_ml   + (size_t)ROWS * 4 * D_MODEL * 2;    // 8 MB each (max 4M elems)
    const size_t o_wtl  = o_wth  + (size_t)4 * 1024 * 1024 * 2;
    const size_t o_tokh = o_wtl  + (size_t)4 * 1024 * 1024 * 2;       // 103 MB each
    const size_t o_tokl = o_tokh + (size_t)VPAD * D_MODEL * 2;
    const size_t need   = o_tokl + (size_t)VPAD * D_MODEL * 2;        // ~307 MB

    char* base = (char*)d_ws;

    if (ws_size >= need) {
        // ================= split-bf16 MFMA path =================
        float* x   = (float*)(base + o_x);
        float* qkv = (float*)(base + o_qkv);
        unsigned short* hh   = (unsigned short*)(base + o_hh);
        unsigned short* hl   = (unsigned short*)(base + o_hl);
        unsigned short* ah   = (unsigned short*)(base + o_ah);
        unsigned short* al   = (unsigned short*)(base + o_al);
        unsigned short* mh   = (unsigned short*)(base + o_mh);
        unsigned short* ml   = (unsigned short*)(base + o_ml);
        unsigned short* wth  = (unsigned short*)(base + o_wth);
        unsigned short* wtl  = (unsigned short*)(base + o_wtl);
        unsigned short* tokh = (unsigned short*)(base + o_tokh);
        unsigned short* tokl = (unsigned short*)(base + o_tokl);

        embed_kernel<<<ROWS, 256, 0, stream>>>(idx, tok, pos, x);
        convrow_kernel<<<VOCAB, 256, 0, stream>>>(tok, tokh, tokl);

        for (int l = 0; l < NLAYER; l++) {
            ln_kernel<<<ROWS, 256, 0, stream>>>(x, ln1_g + l * D_MODEL, ln1_b + l * D_MODEL,
                                                nullptr, hh, hl);
            convtrans_kernel<<<dim3(3 * D_MODEL / 256, D_MODEL / 8), 256, 0, stream>>>(
                qkv_w + (size_t)l * D_MODEL * 3 * D_MODEL, wth, wtl, D_MODEL, 3 * D_MODEL);
            gemm_mfma<<<dim3(3 * D_MODEL / 128, ROWS / 128), 256, 0, stream>>>(
                hh, hl, wth, wtl, nullptr, nullptr, qkv, nullptr, nullptr,
                ROWS, 3 * D_MODEL, D_MODEL, 0);

            attn_kernel<<<dim3(SEQ / QT, BATCH * NHEAD), 256, 0, stream>>>(qkv, nullptr, ah, al);

            convtrans_kernel<<<dim3(D_MODEL / 256, D_MODEL / 8), 256, 0, stream>>>(
                proj_w + (size_t)l * D_MODEL * D_MODEL, wth, wtl, D_MODEL, D_MODEL);
            gemm_mfma<<<dim3(D_MODEL / 128, ROWS / 128), 256, 0, stream>>>(
                ah, al, wth, wtl, nullptr, x, x, nullptr, nullptr,
                ROWS, D_MODEL, D_MODEL, 0);

            ln_kernel<<<ROWS, 256, 0, stream>>>(x, ln2_g + l * D_MODEL, ln2_b + l * D_MODEL,
                                                nullptr, hh, hl);
            convtrans_kernel<<<dim3(4 * D_MODEL / 256, D_MODEL / 8), 256, 0, stream>>>(
                w1 + (size_t)l * D_MODEL * 4 * D_MODEL, wth, wtl, D_MODEL, 4 * D_MODEL);
            gemm_mfma<<<dim3(4 * D_MODEL / 128, ROWS / 128), 256, 0, stream>>>(
                hh, hl, wth, wtl, b1 + (size_t)l * 4 * D_MODEL, nullptr, nullptr, mh, ml,
                ROWS, 4 * D_MODEL, D_MODEL, 1);

            convtrans_kernel<<<dim3(D_MODEL / 256, 4 * D_MODEL / 8), 256, 0, stream>>>(
                w2 + (size_t)l * 4 * D_MODEL * D_MODEL, wth, wtl, 4 * D_MODEL, D_MODEL);
            gemm_mfma<<<dim3(D_MODEL / 128, ROWS / 128), 256, 0, stream>>>(
                mh, ml, wth, wtl, b2 + (size_t)l * D_MODEL, x, x, nullptr, nullptr,
                ROWS, D_MODEL, 4 * D_MODEL, 0);
        }

        ln_kernel<<<ROWS, 256, 0, stream>>>(x, lnf_g, lnf_b, nullptr, hh, hl);
        gemm_mfma<<<dim3(VPAD / 128, ROWS / 128), 256, 0, stream>>>(
            hh, hl, tokh, tokl, nullptr, nullptr, out, nullptr, nullptr,
            ROWS, VOCAB, D_MODEL, 0);
    } else {
        // ================= fp32 VALU fallback (R1) =================
        float* x    = (float*)base;
        float* h    = x    + (size_t)ROWS * D_MODEL;
        float* qkv  = h    + (size_t)ROWS * D_MODEL;
        float* attn = qkv  + (size_t)ROWS * 3 * D_MODEL;
        float* mid  = attn + (size_t)ROWS * D_MODEL;

        embed_kernel<<<ROWS, 256, 0, stream>>>(idx, tok, pos, x);
        for (int l = 0; l < NLAYER; l++) {
            ln_kernel<<<ROWS, 256, 0, stream>>>(x, ln1_g + l * D_MODEL, ln1_b + l * D_MODEL,
                                                h, nullptr, nullptr);
            dim3 gq(3 * D_MODEL / 128, ROWS / 64);
            gemm_kernel<4, 8, false><<<gq, 256, 0, stream>>>(
                h, qkv_w + (size_t)l * D_MODEL * 3 * D_MODEL, nullptr, nullptr,
                qkv, ROWS, 3 * D_MODEL, D_MODEL, 0);
            attn_kernel<<<dim3(SEQ / QT, BATCH * NHEAD), 256, 0, stream>>>(qkv, attn, nullptr, nullptr);
            dim3 gp(D_MODEL / 128, ROWS / 64);
            gemm_kernel<4, 8, false><<<gp, 256, 0, stream>>>(
                attn, proj_w + (size_t)l * D_MODEL * D_MODEL, nullptr, x,
                x, ROWS, D_MODEL, D_MODEL, 0);
            ln_kernel<<<ROWS, 256, 0, stream>>>(x, ln2_g + l * D_MODEL, ln2_b + l * D_MODEL,
                                                h, nullptr, nullptr);
            dim3 gf1(4 * D_MODEL / 128, ROWS / 128);
            gemm_kernel<8, 8, false><<<gf1, 256, 0, stream>>>(
                h, w1 + (size_t)l * D_MODEL * 4 * D_MODEL, b1 + (size_t)l * 4 * D_MODEL, nullptr,
                mid, ROWS, 4 * D_MODEL, D_MODEL, 1);
            gemm_kernel<4, 8, false><<<gp, 256, 0, stream>>>(
                mid, w2 + (size_t)l * 4 * D_MODEL * D_MODEL, b2 + (size_t)l * D_MODEL, x,
                x, ROWS, D_MODEL, 4 * D_MODEL, 0);
        }
        ln_kernel<<<ROWS, 256, 0, stream>>>(x, lnf_g, lnf_b, h, nullptr, nullptr);
        dim3 gl((VOCAB + 127) / 128, ROWS / 128);
        gemm_kernel<8, 8, true><<<gl, 256, 0, stream>>>(
            h, tok, nullptr, nullptr, out, ROWS, VOCAB, D_MODEL, 0);
    }

    hipMemsetAsync(out + (size_t)ROWS * VOCAB, 0, sizeof(float), stream);
    loss_kernel<<<ROWS, 256, 0, stream>>>(out, targets, out + (size_t)ROWS * VOCAB);
}